// Round 14
// baseline (137.589 us; speedup 1.0000x reference)
//
#include <hip/hip_runtime.h>
#include <hip/hip_bf16.h>
#include <hip/hip_fp8.h>
#include <cstdint>
#include <cstddef>

// Problem constants (x = (8192, 768) fp32)
#define GN 8192
#define GD 768           // elements per row; fp8 => 768 bytes per row
#define NB 64            // 128-row blocks
#define NTILE 2080       // NB*(NB+1)/2 triangular tiles
#define KI 12            // 768 / 64 : K-iterations, 64 bytes (2 MFMA k-steps) each

#define LOG2E 1.4426950408889634f
#define LN2 0.6931471805599453f

typedef __attribute__((ext_vector_type(4))) float f32x4;
typedef __attribute__((ext_vector_type(2))) long l64x2;  // one b128 = 2 fp8 fragments

typedef __attribute__((address_space(1))) const unsigned int gu32;
typedef __attribute__((address_space(3))) unsigned int lu32;

__device__ __forceinline__ void gl2lds16(const void* g, void* l) {
    // async global->LDS, 16B per lane; LDS dest is wave-uniform base + lane*16
    __builtin_amdgcn_global_load_lds((gu32*)g, (lu32*)l, 16, 0, 0);
}

// DPP rotate within each 16-lane row (VALU pipe, not DS): dpp_ctrl = 0x120|n.
template <int CTRL>
__device__ __forceinline__ float fdpp(float x) {
    return __int_as_float(__builtin_amdgcn_update_dpp(
        0, __float_as_int(x), CTRL, 0xF, 0xF, true));
}
__device__ __forceinline__ float qmax16(float v) {
    v = fmaxf(v, fdpp<0x128>(v));  // row_ror:8
    v = fmaxf(v, fdpp<0x124>(v));  // row_ror:4
    v = fmaxf(v, fdpp<0x122>(v));  // row_ror:2
    v = fmaxf(v, fdpp<0x121>(v));  // row_ror:1
    return v;
}
__device__ __forceinline__ float qsum16(float v) {
    v += fdpp<0x128>(v);
    v += fdpp<0x124>(v);
    v += fdpp<0x122>(v);
    v += fdpp<0x121>(v);
    return v;
}

// R4/R9's PROVEN swizzle (measured 1.9e5 conflicts), byte-identical:
__device__ __forceinline__ int swz(int r, int q) {
    return ((r >> 1) << 7) + (((((r & 1) << 2) | q) ^ ((r >> 1) & 7)) << 4);
}

// ---------------- Kernel 1: fp8 e4m3 quantize + row sum-of-squares of the
// DEQUANTIZED values (sim_ij = -||x^_i - x^_j||^2 - 100*diag exactly) -------
__global__ __launch_bounds__(256) void prep_kernel(const float* __restrict__ x,
                                                   unsigned char* __restrict__ xq,
                                                   float* __restrict__ sq,
                                                   float* __restrict__ out) {
    if (blockIdx.x == 0 && threadIdx.x == 0) out[0] = 0.f;  // for combine's atomics
    const int w = threadIdx.x >> 6, lane = threadIdx.x & 63;
    const int row = blockIdx.x * 4 + w;
    const float4* xr = (const float4*)(x + (size_t)row * GD);
    unsigned int* xqr = (unsigned int*)(xq + (size_t)row * GD);
    float s = 0.f;
#pragma unroll
    for (int i = 0; i < 3; ++i) {
        float4 v = xr[lane + 64 * i];
        __hip_fp8_e4m3 q0(v.x), q1(v.y), q2(v.z), q3(v.w);
        float d0 = (float)q0, d1 = (float)q1, d2 = (float)q2, d3 = (float)q3;
        s += d0 * d0 + d1 * d1 + d2 * d2 + d3 * d3;
        xqr[lane + 64 * i] = (unsigned int)q0.__x | ((unsigned int)q1.__x << 8) |
                             ((unsigned int)q2.__x << 16) | ((unsigned int)q3.__x << 24);
    }
#pragma unroll
    for (int off = 1; off < 64; off <<= 1) s += __shfl_xor(s, off);
    if (lane == 0) sq[row] = s;
}

// ------- Kernel 2: symmetric triangular tile GEMM (fp8, k-paired) + entropy -------
// R12/R13's proven core. Change: softmax state in BASE 2 (log2e folded into the
// affine constants) -> every exp is a bare v_exp_f32 (exp2), no per-exp mul.
// Partials (m2,S,T2) are base-2; combine converts with a single ln2 at the end.
// C/D: col=lane&15, row=(lane>>4)*4+reg (dtype-independent, verified).
__global__ __launch_bounds__(256, 4) void sym_gemm_entropy(
    const unsigned char* __restrict__ xq, const float* __restrict__ sq,
    const float* __restrict__ taup, float* __restrict__ pm,
    float* __restrict__ ps, float* __restrict__ pt) {
    __shared__ __align__(16) char lds[32768];  // [A0 8K][B0 8K][A1 8K][B1 8K]
    float (*tmrg)[4][3] = (float (*)[4][3])lds;  // aliased; guarded by barrier

    const int tid = threadIdx.x;
    const int lane = tid & 63;
    const int w = tid >> 6;
    const int quad = lane >> 4, cl = lane & 15;

    const int b = blockIdx.x;
    int I = (int)((sqrtf(8.0f * (float)b + 1.0f) - 1.0f) * 0.5f);
    while ((I + 1) * (I + 2) / 2 <= b) ++I;
    while (I * (I + 1) / 2 > b) --I;
    const int J = b - I * (I + 1) / 2;
    const int row_base = I * 128;
    const int col_base = J * 128;
    const float taub = (*taup) * LOG2E;  // base-2 scale

    // staging decode (proven inverse-swizzle)
    const int bb = (tid & 7) ^ ((tid >> 3) & 7);
    const int sRow = ((tid >> 3) << 1) | (bb >> 2);  // 0..63
    const int sKb = (bb & 3) * 16;                   // byte offset in 64-B chunk
    const unsigned char* gA = xq + (size_t)(row_base + sRow) * GD + sKb;
    const unsigned char* gB = xq + (size_t)(col_base + sRow) * GD + sKb;

    // fragment LDS offsets (one b128 per tile-row): unit q = quad
    int offA[2], offB[8];
#pragma unroll
    for (int ti = 0; ti < 2; ++ti) offA[ti] = swz(w * 32 + ti * 16 + cl, quad);
#pragma unroll
    for (int tj = 0; tj < 8; ++tj) offB[tj] = swz(tj * 16 + cl, quad);

    f32x4 acc[2][8];
#pragma unroll
    for (int i = 0; i < 2; ++i)
#pragma unroll
        for (int j = 0; j < 8; ++j) acc[i][j] = (f32x4){0.f, 0.f, 0.f, 0.f};

    // prologue: stage k=0 into buffer 0
    gl2lds16(gA, lds + tid * 16);
    gl2lds16(gA + (size_t)64 * GD, lds + 4096 + tid * 16);
    gl2lds16(gB, lds + 8192 + tid * 16);
    gl2lds16(gB + (size_t)64 * GD, lds + 12288 + tid * 16);

#pragma unroll 2
    for (int kk = 0; kk < KI; ++kk) {
        __syncthreads();  // buf[kk&1] staged; prior buf's ds_reads done

        // 1) read ALL fragments of this iter (10 x ds_read_b128)
        const char* Ab = lds + (kk & 1) * 16384;
        const char* Bb = Ab + 8192;
        l64x2 aF[2], bF[8];
#pragma unroll
        for (int ti = 0; ti < 2; ++ti) aF[ti] = *(const l64x2*)(Ab + offA[ti]);
#pragma unroll
        for (int tj = 0; tj < 8; ++tj) bF[tj] = *(const l64x2*)(Bb + offB[tj]);

        // 2) stage k+1 into the other buffer; drains at the next barrier
        if (kk + 1 < KI) {
            char* An = lds + ((kk + 1) & 1) * 16384;
            const int ko = (kk + 1) * 64;  // bytes along K
            gl2lds16(gA + ko, An + tid * 16);
            gl2lds16(gA + (size_t)64 * GD + ko, An + 4096 + tid * 16);
            gl2lds16(gB + ko, An + 8192 + tid * 16);
            gl2lds16(gB + (size_t)64 * GD + ko, An + 12288 + tid * 16);
        }

        // 3) 32 MFMAs: each b128 pair feeds two K=32 fp8 MFMAs
#pragma unroll
        for (int ti = 0; ti < 2; ++ti)
#pragma unroll
            for (int tj = 0; tj < 8; ++tj) {
                acc[ti][tj] = __builtin_amdgcn_mfma_f32_16x16x32_fp8_fp8(
                    aF[ti].x, bF[tj].x, acc[ti][tj], 0, 0, 0);
                acc[ti][tj] = __builtin_amdgcn_mfma_f32_16x16x32_fp8_fp8(
                    aF[ti].y, bF[tj].y, acc[ti][tj], 0, 0, 0);
            }
    }

    // ---------------- epilogue (all softmax state in BASE 2) ----------------
    const float t2 = 2.f * taub;
    const float pen = 100.f * taub;
    float ar[8];  // -taub * sq[row] for this lane's 8 rows
    int rowg[8];
#pragma unroll
    for (int ti = 0; ti < 2; ++ti)
#pragma unroll
        for (int rg = 0; rg < 4; ++rg) {
            int r = row_base + w * 32 + ti * 16 + quad * 4 + rg;
            rowg[ti * 4 + rg] = r;
            ar[ti * 4 + rg] = -taub * sq[r];
        }
    float ac[8];  // -taub * sq[col] for this lane's 8 cols
#pragma unroll
    for (int tj = 0; tj < 8; ++tj) ac[tj] = -taub * sq[col_base + tj * 16 + cl];

    float* pmJ = pm + (size_t)J * GN;
    float* psJ = ps + (size_t)J * GN;
    float* ptJ = pt + (size_t)J * GN;

    // ---- direct pass: one (m2,S,T2) per row of block I over J's 128 cols ----
#pragma unroll
    for (int ti = 0; ti < 2; ++ti)
#pragma unroll
        for (int rg = 0; rg < 4; ++rg) {
            const int idx = ti * 4 + rg;
            const float base = ar[idx];
            float vv[8];
            float mloc = -1e30f;
            if (I == J) {  // block-uniform: only diagonal tiles carry the penalty
#pragma unroll
                for (int tj = 0; tj < 8; ++tj) {
                    float v = fmaf(t2, acc[ti][tj][rg], base + ac[tj]);
                    if (rowg[idx] == col_base + tj * 16 + cl) v -= pen;
                    vv[tj] = v;
                    mloc = fmaxf(mloc, v);
                }
            } else {
#pragma unroll
                for (int tj = 0; tj < 8; ++tj) {
                    float v = fmaf(t2, acc[ti][tj][rg], base + ac[tj]);
                    vv[tj] = v;
                    mloc = fmaxf(mloc, v);
                }
            }
            mloc = qmax16(mloc);
            float s = 0.f, t = 0.f;
#pragma unroll
            for (int tj = 0; tj < 8; ++tj) {
                float d = vv[tj] - mloc;          // base-2 exponent
                float e = __builtin_exp2f(d);     // bare v_exp_f32
                s += e;
                t += e * d;
            }
            s = qsum16(s);
            t = qsum16(t);
            if (cl == 0) {
                int r = rowg[idx];
                pmJ[r] = mloc;
                psJ[r] = s;
                ptJ[r] = t;
            }
        }

    // ---- transposed pass (off-diagonal tiles): rows of block J over I's rows ----
    if (I != J) {  // block-uniform branch
        __syncthreads();  // all K-loop LDS reads done before tmrg aliases the buffer
#pragma unroll
        for (int tj = 0; tj < 8; ++tj) {
            const float cbase = ac[tj];
            float vv[8];
            float mloc = -1e30f;
#pragma unroll
            for (int ti = 0; ti < 2; ++ti)
#pragma unroll
                for (int rg = 0; rg < 4; ++rg) {
                    float v = fmaf(t2, acc[ti][tj][rg], ar[ti * 4 + rg] + cbase);
                    vv[ti * 4 + rg] = v;
                    mloc = fmaxf(mloc, v);
                }
            mloc = fmaxf(mloc, __shfl_xor(mloc, 16));
            mloc = fmaxf(mloc, __shfl_xor(mloc, 32));
            float s = 0.f, t = 0.f;
#pragma unroll
            for (int k = 0; k < 8; ++k) {
                float d = vv[k] - mloc;
                float e = __builtin_exp2f(d);
                s += e;
                t += e * d;
            }
            s += __shfl_xor(s, 16);
            t += __shfl_xor(t, 16);
            s += __shfl_xor(s, 32);
            t += __shfl_xor(t, 32);
            if (quad == 0) {
                int c = tj * 16 + cl;
                tmrg[c][w][0] = mloc;
                tmrg[c][w][1] = s;
                tmrg[c][w][2] = t;
            }
        }
        __syncthreads();
        if (tid < 128) {
            float m = tmrg[tid][0][0], S = tmrg[tid][0][1], T = tmrg[tid][0][2];
#pragma unroll
            for (int ww = 1; ww < 4; ++ww) {
                float mc = tmrg[tid][ww][0], Sc = tmrg[tid][ww][1], Tc = tmrg[tid][ww][2];
                float mn = fmaxf(m, mc);
                float ea = __builtin_exp2f(m - mn), eb = __builtin_exp2f(mc - mn);
                T = (T + (m - mn) * S) * ea + (Tc + (mc - mn) * Sc) * eb;
                S = S * ea + Sc * eb;
                m = mn;
            }
            int c = col_base + tid;
            pm[(size_t)I * GN + c] = m;
            ps[(size_t)I * GN + c] = S;
            pt[(size_t)I * GN + c] = T;
        }
    }
}

// ------- Kernel 3: combine (base-2), coalesced + parallel -------
// entropy = ln2 * (log2(S) - T2/S); ln2 folded into the final atomic constant.
__global__ __launch_bounds__(256) void combine(const float* __restrict__ pm,
                                               const float* __restrict__ ps,
                                               const float* __restrict__ pt,
                                               const float* __restrict__ coefp,
                                               float* __restrict__ out) {
    const int t = threadIdx.x;
    const int r = t & 63;
    const int chunk = t >> 6;
    const int row = blockIdx.x * 64 + r;
    float m = -1e30f, S = 0.f, T = 0.f;
#pragma unroll
    for (int i = 0; i < 16; ++i) {
        const int c = chunk * 16 + i;
        float mc = pm[(size_t)c * GN + row];
        float Sc = ps[(size_t)c * GN + row];
        float Tc = pt[(size_t)c * GN + row];
        float mn = fmaxf(m, mc);
        float ea = __builtin_exp2f(m - mn), eb = __builtin_exp2f(mc - mn);
        T = (T + (m - mn) * S) * ea + (Tc + (mc - mn) * Sc) * eb;
        S = S * ea + Sc * eb;
        m = mn;
    }
    __shared__ float lm[4][64], lS[4][64], lT[4][64];
    lm[chunk][r] = m;
    lS[chunk][r] = S;
    lT[chunk][r] = T;
    __syncthreads();
    if (t < 64) {
        float M = lm[0][r], Sa = lS[0][r], Ta = lT[0][r];
#pragma unroll
        for (int cc = 1; cc < 4; ++cc) {
            float mc = lm[cc][r], Sc = lS[cc][r], Tc = lT[cc][r];
            float mn = fmaxf(M, mc);
            float ea = __builtin_exp2f(M - mn), eb = __builtin_exp2f(mc - mn);
            Ta = (Ta + (M - mn) * Sa) * ea + (Tc + (mc - mn) * Sc) * eb;
            Sa = Sa * ea + Sc * eb;
            M = mn;
        }
        float ent2 = __builtin_log2f(Sa) - Ta / Sa;  // base-2 row entropy
#pragma unroll
        for (int off = 1; off < 64; off <<= 1) ent2 += __shfl_xor(ent2, off);
        if (t == 0) atomicAdd(out, ent2 * coefp[0] * (LN2 / (float)GN));
    }
}

extern "C" void kernel_launch(void* const* d_in, const int* in_sizes, int n_in,
                              void* d_out, int out_size, void* d_ws, size_t ws_size,
                              hipStream_t stream) {
    const float* x = (const float*)d_in[0];      // 8192*768 fp32
    const float* coefp = (const float*)d_in[1];  // scalar
    const float* taup = (const float*)d_in[2];   // scalar
    float* out = (float*)d_out;

    char* ws = (char*)d_ws;
    unsigned char* xq = (unsigned char*)ws;              // 6,291,456 B (fp8)
    float* sq = (float*)(ws + 6291456);                  // 32,768 B
    float* pm = (float*)(ws + 6324224);                  // 2,097,152 B
    float* ps = (float*)(ws + 6324224 + 2097152);        // 2,097,152 B
    float* pt = (float*)(ws + 6324224 + 2 * 2097152);    // 2,097,152 B

    prep_kernel<<<GN / 4, 256, 0, stream>>>(x, xq, sq, out);
    sym_gemm_entropy<<<NTILE, 256, 0, stream>>>(xq, sq, taup, pm, ps, pt);
    combine<<<GN / 64, 256, 0, stream>>>(pm, ps, pt, coefp, out);
}

// Round 15
// 131.964 us; speedup vs baseline: 1.0426x; 1.0426x over previous
//
#include <hip/hip_runtime.h>
#include <hip/hip_bf16.h>
#include <hip/hip_fp8.h>
#include <cstdint>
#include <cstddef>

// Problem constants (x = (8192, 768) fp32)
#define GN 8192
#define GD 768           // elements per row; fp8 => 768 bytes per row
#define NB 64            // 128-row blocks
#define NTILE 2080       // NB*(NB+1)/2 triangular tiles
#define KI 12            // 768 / 64 : K-iterations, 64 bytes (2 MFMA k-steps) each

#define LOG2E 1.4426950408889634f
#define LN2 0.6931471805599453f

typedef __attribute__((ext_vector_type(4))) float f32x4;
typedef __attribute__((ext_vector_type(2))) long l64x2;  // one b128 = 2 fp8 fragments

typedef __attribute__((address_space(1))) const unsigned int gu32;
typedef __attribute__((address_space(3))) unsigned int lu32;

__device__ __forceinline__ void gl2lds16(const void* g, void* l) {
    // async global->LDS, 16B per lane; LDS dest is wave-uniform base + lane*16
    __builtin_amdgcn_global_load_lds((gu32*)g, (lu32*)l, 16, 0, 0);
}

// bare v_exp_f32 (exp2) -- the CK softmax path; no OCML fixup, no ln->log2 mul
__device__ __forceinline__ float hexp2(float x) {
    return __builtin_amdgcn_exp2f(x);
}

// DPP rotate within each 16-lane row (VALU pipe, not DS): dpp_ctrl = 0x120|n.
template <int CTRL>
__device__ __forceinline__ float fdpp(float x) {
    return __int_as_float(__builtin_amdgcn_update_dpp(
        0, __float_as_int(x), CTRL, 0xF, 0xF, true));
}
__device__ __forceinline__ float qmax16(float v) {
    v = fmaxf(v, fdpp<0x128>(v));  // row_ror:8
    v = fmaxf(v, fdpp<0x124>(v));  // row_ror:4
    v = fmaxf(v, fdpp<0x122>(v));  // row_ror:2
    v = fmaxf(v, fdpp<0x121>(v));  // row_ror:1
    return v;
}
__device__ __forceinline__ float qsum16(float v) {
    v += fdpp<0x128>(v);
    v += fdpp<0x124>(v);
    v += fdpp<0x122>(v);
    v += fdpp<0x121>(v);
    return v;
}

// R4/R9's PROVEN swizzle (measured 1.9e5 conflicts), byte-identical:
__device__ __forceinline__ int swz(int r, int q) {
    return ((r >> 1) << 7) + (((((r & 1) << 2) | q) ^ ((r >> 1) & 7)) << 4);
}

// ---------------- Kernel 1: fp8 e4m3 quantize + row sum-of-squares of the
// DEQUANTIZED values (sim_ij = -||x^_i - x^_j||^2 - 100*diag exactly) -------
__global__ __launch_bounds__(256) void prep_kernel(const float* __restrict__ x,
                                                   unsigned char* __restrict__ xq,
                                                   float* __restrict__ sq,
                                                   float* __restrict__ out) {
    if (blockIdx.x == 0 && threadIdx.x == 0) out[0] = 0.f;  // for combine's atomics
    const int w = threadIdx.x >> 6, lane = threadIdx.x & 63;
    const int row = blockIdx.x * 4 + w;
    const float4* xr = (const float4*)(x + (size_t)row * GD);
    unsigned int* xqr = (unsigned int*)(xq + (size_t)row * GD);
    float s = 0.f;
#pragma unroll
    for (int i = 0; i < 3; ++i) {
        float4 v = xr[lane + 64 * i];
        __hip_fp8_e4m3 q0(v.x), q1(v.y), q2(v.z), q3(v.w);
        float d0 = (float)q0, d1 = (float)q1, d2 = (float)q2, d3 = (float)q3;
        s += d0 * d0 + d1 * d1 + d2 * d2 + d3 * d3;
        xqr[lane + 64 * i] = (unsigned int)q0.__x | ((unsigned int)q1.__x << 8) |
                             ((unsigned int)q2.__x << 16) | ((unsigned int)q3.__x << 24);
    }
#pragma unroll
    for (int off = 1; off < 64; off <<= 1) s += __shfl_xor(s, off);
    if (lane == 0) sq[row] = s;
}

// ------- Kernel 2: symmetric triangular tile GEMM (fp8, k-paired) + entropy -------
// R12/R13's proven core; softmax state in BASE 2 with BARE v_exp_f32
// (__builtin_amdgcn_exp2f -- R14's __builtin_exp2f went through OCML and
// regressed; this is the 1-inst hardware path).
// C/D: col=lane&15, row=(lane>>4)*4+reg (dtype-independent, verified).
__global__ __launch_bounds__(256, 4) void sym_gemm_entropy(
    const unsigned char* __restrict__ xq, const float* __restrict__ sq,
    const float* __restrict__ taup, float* __restrict__ pm,
    float* __restrict__ ps, float* __restrict__ pt) {
    __shared__ __align__(16) char lds[32768];  // [A0 8K][B0 8K][A1 8K][B1 8K]
    float (*tmrg)[4][3] = (float (*)[4][3])lds;  // aliased; guarded by barrier

    const int tid = threadIdx.x;
    const int lane = tid & 63;
    const int w = tid >> 6;
    const int quad = lane >> 4, cl = lane & 15;

    const int b = blockIdx.x;
    int I = (int)((sqrtf(8.0f * (float)b + 1.0f) - 1.0f) * 0.5f);
    while ((I + 1) * (I + 2) / 2 <= b) ++I;
    while (I * (I + 1) / 2 > b) --I;
    const int J = b - I * (I + 1) / 2;
    const int row_base = I * 128;
    const int col_base = J * 128;
    const float taub = (*taup) * LOG2E;  // base-2 scale

    // staging decode (proven inverse-swizzle)
    const int bb = (tid & 7) ^ ((tid >> 3) & 7);
    const int sRow = ((tid >> 3) << 1) | (bb >> 2);  // 0..63
    const int sKb = (bb & 3) * 16;                   // byte offset in 64-B chunk
    const unsigned char* gA = xq + (size_t)(row_base + sRow) * GD + sKb;
    const unsigned char* gB = xq + (size_t)(col_base + sRow) * GD + sKb;

    // fragment LDS offsets (one b128 per tile-row): unit q = quad
    int offA[2], offB[8];
#pragma unroll
    for (int ti = 0; ti < 2; ++ti) offA[ti] = swz(w * 32 + ti * 16 + cl, quad);
#pragma unroll
    for (int tj = 0; tj < 8; ++tj) offB[tj] = swz(tj * 16 + cl, quad);

    f32x4 acc[2][8];
#pragma unroll
    for (int i = 0; i < 2; ++i)
#pragma unroll
        for (int j = 0; j < 8; ++j) acc[i][j] = (f32x4){0.f, 0.f, 0.f, 0.f};

    // prologue: stage k=0 into buffer 0
    gl2lds16(gA, lds + tid * 16);
    gl2lds16(gA + (size_t)64 * GD, lds + 4096 + tid * 16);
    gl2lds16(gB, lds + 8192 + tid * 16);
    gl2lds16(gB + (size_t)64 * GD, lds + 12288 + tid * 16);

#pragma unroll 2
    for (int kk = 0; kk < KI; ++kk) {
        __syncthreads();  // buf[kk&1] staged; prior buf's ds_reads done

        // 1) read ALL fragments of this iter (10 x ds_read_b128)
        const char* Ab = lds + (kk & 1) * 16384;
        const char* Bb = Ab + 8192;
        l64x2 aF[2], bF[8];
#pragma unroll
        for (int ti = 0; ti < 2; ++ti) aF[ti] = *(const l64x2*)(Ab + offA[ti]);
#pragma unroll
        for (int tj = 0; tj < 8; ++tj) bF[tj] = *(const l64x2*)(Bb + offB[tj]);

        // 2) stage k+1 into the other buffer; drains at the next barrier
        if (kk + 1 < KI) {
            char* An = lds + ((kk + 1) & 1) * 16384;
            const int ko = (kk + 1) * 64;  // bytes along K
            gl2lds16(gA + ko, An + tid * 16);
            gl2lds16(gA + (size_t)64 * GD + ko, An + 4096 + tid * 16);
            gl2lds16(gB + ko, An + 8192 + tid * 16);
            gl2lds16(gB + (size_t)64 * GD + ko, An + 12288 + tid * 16);
        }

        // 3) 32 MFMAs: each b128 pair feeds two K=32 fp8 MFMAs
#pragma unroll
        for (int ti = 0; ti < 2; ++ti)
#pragma unroll
            for (int tj = 0; tj < 8; ++tj) {
                acc[ti][tj] = __builtin_amdgcn_mfma_f32_16x16x32_fp8_fp8(
                    aF[ti].x, bF[tj].x, acc[ti][tj], 0, 0, 0);
                acc[ti][tj] = __builtin_amdgcn_mfma_f32_16x16x32_fp8_fp8(
                    aF[ti].y, bF[tj].y, acc[ti][tj], 0, 0, 0);
            }
    }

    // ---------------- epilogue (all softmax state in BASE 2) ----------------
    const float t2 = 2.f * taub;
    const float pen = 100.f * taub;
    float ar[8];  // -taub * sq[row] for this lane's 8 rows
    int rowg[8];
#pragma unroll
    for (int ti = 0; ti < 2; ++ti)
#pragma unroll
        for (int rg = 0; rg < 4; ++rg) {
            int r = row_base + w * 32 + ti * 16 + quad * 4 + rg;
            rowg[ti * 4 + rg] = r;
            ar[ti * 4 + rg] = -taub * sq[r];
        }
    float ac[8];  // -taub * sq[col] for this lane's 8 cols
#pragma unroll
    for (int tj = 0; tj < 8; ++tj) ac[tj] = -taub * sq[col_base + tj * 16 + cl];

    float* pmJ = pm + (size_t)J * GN;
    float* psJ = ps + (size_t)J * GN;
    float* ptJ = pt + (size_t)J * GN;

    // ---- direct pass: one (m2,S,T2) per row of block I over J's 128 cols ----
#pragma unroll
    for (int ti = 0; ti < 2; ++ti)
#pragma unroll
        for (int rg = 0; rg < 4; ++rg) {
            const int idx = ti * 4 + rg;
            const float base = ar[idx];
            float vv[8];
            float mloc = -1e30f;
            if (I == J) {  // block-uniform: only diagonal tiles carry the penalty
#pragma unroll
                for (int tj = 0; tj < 8; ++tj) {
                    float v = fmaf(t2, acc[ti][tj][rg], base + ac[tj]);
                    if (rowg[idx] == col_base + tj * 16 + cl) v -= pen;
                    vv[tj] = v;
                    mloc = fmaxf(mloc, v);
                }
            } else {
#pragma unroll
                for (int tj = 0; tj < 8; ++tj) {
                    float v = fmaf(t2, acc[ti][tj][rg], base + ac[tj]);
                    vv[tj] = v;
                    mloc = fmaxf(mloc, v);
                }
            }
            mloc = qmax16(mloc);
            float s = 0.f, t = 0.f;
#pragma unroll
            for (int tj = 0; tj < 8; ++tj) {
                float d = vv[tj] - mloc;  // base-2 exponent
                float e = hexp2(d);       // bare v_exp_f32
                s += e;
                t += e * d;
            }
            s = qsum16(s);
            t = qsum16(t);
            if (cl == 0) {
                int r = rowg[idx];
                pmJ[r] = mloc;
                psJ[r] = s;
                ptJ[r] = t;
            }
        }

    // ---- transposed pass (off-diagonal tiles): rows of block J over I's rows ----
    if (I != J) {  // block-uniform branch
        __syncthreads();  // all K-loop LDS reads done before tmrg aliases the buffer
#pragma unroll
        for (int tj = 0; tj < 8; ++tj) {
            const float cbase = ac[tj];
            float vv[8];
            float mloc = -1e30f;
#pragma unroll
            for (int ti = 0; ti < 2; ++ti)
#pragma unroll
                for (int rg = 0; rg < 4; ++rg) {
                    float v = fmaf(t2, acc[ti][tj][rg], ar[ti * 4 + rg] + cbase);
                    vv[ti * 4 + rg] = v;
                    mloc = fmaxf(mloc, v);
                }
            mloc = fmaxf(mloc, __shfl_xor(mloc, 16));
            mloc = fmaxf(mloc, __shfl_xor(mloc, 32));
            float s = 0.f, t = 0.f;
#pragma unroll
            for (int k = 0; k < 8; ++k) {
                float d = vv[k] - mloc;
                float e = hexp2(d);
                s += e;
                t += e * d;
            }
            s += __shfl_xor(s, 16);
            t += __shfl_xor(t, 16);
            s += __shfl_xor(s, 32);
            t += __shfl_xor(t, 32);
            if (quad == 0) {
                int c = tj * 16 + cl;
                tmrg[c][w][0] = mloc;
                tmrg[c][w][1] = s;
                tmrg[c][w][2] = t;
            }
        }
        __syncthreads();
        if (tid < 128) {
            float m = tmrg[tid][0][0], S = tmrg[tid][0][1], T = tmrg[tid][0][2];
#pragma unroll
            for (int ww = 1; ww < 4; ++ww) {
                float mc = tmrg[tid][ww][0], Sc = tmrg[tid][ww][1], Tc = tmrg[tid][ww][2];
                float mn = fmaxf(m, mc);
                float ea = hexp2(m - mn), eb = hexp2(mc - mn);
                T = (T + (m - mn) * S) * ea + (Tc + (mc - mn) * Sc) * eb;
                S = S * ea + Sc * eb;
                m = mn;
            }
            int c = col_base + tid;
            pm[(size_t)I * GN + c] = m;
            ps[(size_t)I * GN + c] = S;
            pt[(size_t)I * GN + c] = T;
        }
    }
}

// ------- Kernel 3: combine (base-2), coalesced + parallel -------
// entropy = ln2 * (log2(S) - T2/S); ln2 folded into the final atomic constant.
__global__ __launch_bounds__(256) void combine(const float* __restrict__ pm,
                                               const float* __restrict__ ps,
                                               const float* __restrict__ pt,
                                               const float* __restrict__ coefp,
                                               float* __restrict__ out) {
    const int t = threadIdx.x;
    const int r = t & 63;
    const int chunk = t >> 6;
    const int row = blockIdx.x * 64 + r;
    float m = -1e30f, S = 0.f, T = 0.f;
#pragma unroll
    for (int i = 0; i < 16; ++i) {
        const int c = chunk * 16 + i;
        float mc = pm[(size_t)c * GN + row];
        float Sc = ps[(size_t)c * GN + row];
        float Tc = pt[(size_t)c * GN + row];
        float mn = fmaxf(m, mc);
        float ea = __builtin_amdgcn_exp2f(m - mn), eb = __builtin_amdgcn_exp2f(mc - mn);
        T = (T + (m - mn) * S) * ea + (Tc + (mc - mn) * Sc) * eb;
        S = S * ea + Sc * eb;
        m = mn;
    }
    __shared__ float lm[4][64], lS[4][64], lT[4][64];
    lm[chunk][r] = m;
    lS[chunk][r] = S;
    lT[chunk][r] = T;
    __syncthreads();
    if (t < 64) {
        float M = lm[0][r], Sa = lS[0][r], Ta = lT[0][r];
#pragma unroll
        for (int cc = 1; cc < 4; ++cc) {
            float mc = lm[cc][r], Sc = lS[cc][r], Tc = lT[cc][r];
            float mn = fmaxf(M, mc);
            float ea = __builtin_amdgcn_exp2f(M - mn), eb = __builtin_amdgcn_exp2f(mc - mn);
            Ta = (Ta + (M - mn) * Sa) * ea + (Tc + (mc - mn) * Sc) * eb;
            Sa = Sa * ea + Sc * eb;
            M = mn;
        }
        float ent2 = __log2f(Sa) - Ta / Sa;  // base-2 row entropy (v_log_f32)
#pragma unroll
        for (int off = 1; off < 64; off <<= 1) ent2 += __shfl_xor(ent2, off);
        if (t == 0) atomicAdd(out, ent2 * coefp[0] * (LN2 / (float)GN));
    }
}

extern "C" void kernel_launch(void* const* d_in, const int* in_sizes, int n_in,
                              void* d_out, int out_size, void* d_ws, size_t ws_size,
                              hipStream_t stream) {
    const float* x = (const float*)d_in[0];      // 8192*768 fp32
    const float* coefp = (const float*)d_in[1];  // scalar
    const float* taup = (const float*)d_in[2];   // scalar
    float* out = (float*)d_out;

    char* ws = (char*)d_ws;
    unsigned char* xq = (unsigned char*)ws;              // 6,291,456 B (fp8)
    float* sq = (float*)(ws + 6291456);                  // 32,768 B
    float* pm = (float*)(ws + 6324224);                  // 2,097,152 B
    float* ps = (float*)(ws + 6324224 + 2097152);        // 2,097,152 B
    float* pt = (float*)(ws + 6324224 + 2 * 2097152);    // 2,097,152 B

    prep_kernel<<<GN / 4, 256, 0, stream>>>(x, xq, sq, out);
    sym_gemm_entropy<<<NTILE, 256, 0, stream>>>(xq, sq, taup, pm, ps, pt);
    combine<<<GN / 64, 256, 0, stream>>>(pm, ps, pt, coefp, out);
}

// Round 16
// 130.236 us; speedup vs baseline: 1.0565x; 1.0133x over previous
//
#include <hip/hip_runtime.h>
#include <hip/hip_bf16.h>
#include <hip/hip_fp8.h>
#include <cstdint>
#include <cstddef>

// Problem constants (x = (8192, 768) fp32)
#define GN 8192
#define GD 768           // elements per row; fp8 => 768 bytes per row
#define NB 64            // 128-row blocks
#define NTILE 2080       // NB*(NB+1)/2 triangular tiles
#define KI 12            // 768 / 64 : K-iterations, 64 bytes (2 MFMA k-steps) each

#define LOG2E 1.4426950408889634f
#define LN2 0.6931471805599453f

typedef __attribute__((ext_vector_type(4))) float f32x4;
typedef __attribute__((ext_vector_type(2))) long l64x2;  // one b128 = 2 fp8 fragments

typedef __attribute__((address_space(1))) const unsigned int gu32;
typedef __attribute__((address_space(3))) unsigned int lu32;

__device__ __forceinline__ void gl2lds16(const void* g, void* l) {
    // async global->LDS, 16B per lane; LDS dest is wave-uniform base + lane*16
    __builtin_amdgcn_global_load_lds((gu32*)g, (lu32*)l, 16, 0, 0);
}

// bare v_exp_f32 (exp2) -- the 1-inst hardware path (R15-verified)
__device__ __forceinline__ float hexp2(float x) {
    return __builtin_amdgcn_exp2f(x);
}

// DPP rotate within each 16-lane row (VALU pipe, not DS): dpp_ctrl = 0x120|n.
template <int CTRL>
__device__ __forceinline__ float fdpp(float x) {
    return __int_as_float(__builtin_amdgcn_update_dpp(
        0, __float_as_int(x), CTRL, 0xF, 0xF, true));
}
__device__ __forceinline__ float qmax16(float v) {
    v = fmaxf(v, fdpp<0x128>(v));  // row_ror:8
    v = fmaxf(v, fdpp<0x124>(v));  // row_ror:4
    v = fmaxf(v, fdpp<0x122>(v));  // row_ror:2
    v = fmaxf(v, fdpp<0x121>(v));  // row_ror:1
    return v;
}
__device__ __forceinline__ float qsum16(float v) {
    v += fdpp<0x128>(v);
    v += fdpp<0x124>(v);
    v += fdpp<0x122>(v);
    v += fdpp<0x121>(v);
    return v;
}

// R4/R9's PROVEN swizzle (measured 1.9e5 conflicts), byte-identical:
__device__ __forceinline__ int swz(int r, int q) {
    return ((r >> 1) << 7) + (((((r & 1) << 2) | q) ^ ((r >> 1) & 7)) << 4);
}

// ---------------- Kernel 1: fp8 e4m3 quantize + row sum-of-squares of the
// DEQUANTIZED values (sim_ij = -||x^_i - x^_j||^2 - 100*diag exactly) -------
__global__ __launch_bounds__(256) void prep_kernel(const float* __restrict__ x,
                                                   unsigned char* __restrict__ xq,
                                                   float* __restrict__ sq,
                                                   float* __restrict__ out) {
    if (blockIdx.x == 0 && threadIdx.x == 0) out[0] = 0.f;  // for combine's atomics
    const int w = threadIdx.x >> 6, lane = threadIdx.x & 63;
    const int row = blockIdx.x * 4 + w;
    const float4* xr = (const float4*)(x + (size_t)row * GD);
    unsigned int* xqr = (unsigned int*)(xq + (size_t)row * GD);
    float s = 0.f;
#pragma unroll
    for (int i = 0; i < 3; ++i) {
        float4 v = xr[lane + 64 * i];
        __hip_fp8_e4m3 q0(v.x), q1(v.y), q2(v.z), q3(v.w);
        float d0 = (float)q0, d1 = (float)q1, d2 = (float)q2, d3 = (float)q3;
        s += d0 * d0 + d1 * d1 + d2 * d2 + d3 * d3;
        xqr[lane + 64 * i] = (unsigned int)q0.__x | ((unsigned int)q1.__x << 8) |
                             ((unsigned int)q2.__x << 16) | ((unsigned int)q3.__x << 24);
    }
#pragma unroll
    for (int off = 1; off < 64; off <<= 1) s += __shfl_xor(s, off);
    if (lane == 0) sq[row] = s;
}

// ------- Kernel 2: symmetric triangular tile GEMM (fp8, k-paired) + entropy -------
// R15's proven core. Change: BASE-CANCELLATION -- the row term (direct pass) /
// col term (transposed pass) is uniform across each reduction group, so it
// cancels in d = v - max(v). Compute u without it; add it once into stored m.
// Removes ~128 v_add/thread.
// C/D: col=lane&15, row=(lane>>4)*4+reg (dtype-independent, verified).
__global__ __launch_bounds__(256, 4) void sym_gemm_entropy(
    const unsigned char* __restrict__ xq, const float* __restrict__ sq,
    const float* __restrict__ taup, float* __restrict__ pm,
    float* __restrict__ ps, float* __restrict__ pt) {
    __shared__ __align__(16) char lds[32768];  // [A0 8K][B0 8K][A1 8K][B1 8K]
    float (*tmrg)[4][3] = (float (*)[4][3])lds;  // aliased; guarded by barrier

    const int tid = threadIdx.x;
    const int lane = tid & 63;
    const int w = tid >> 6;
    const int quad = lane >> 4, cl = lane & 15;

    const int b = blockIdx.x;
    int I = (int)((sqrtf(8.0f * (float)b + 1.0f) - 1.0f) * 0.5f);
    while ((I + 1) * (I + 2) / 2 <= b) ++I;
    while (I * (I + 1) / 2 > b) --I;
    const int J = b - I * (I + 1) / 2;
    const int row_base = I * 128;
    const int col_base = J * 128;
    const float taub = (*taup) * LOG2E;  // base-2 scale

    // staging decode (proven inverse-swizzle)
    const int bb = (tid & 7) ^ ((tid >> 3) & 7);
    const int sRow = ((tid >> 3) << 1) | (bb >> 2);  // 0..63
    const int sKb = (bb & 3) * 16;                   // byte offset in 64-B chunk
    const unsigned char* gA = xq + (size_t)(row_base + sRow) * GD + sKb;
    const unsigned char* gB = xq + (size_t)(col_base + sRow) * GD + sKb;

    // fragment LDS offsets (one b128 per tile-row): unit q = quad
    int offA[2], offB[8];
#pragma unroll
    for (int ti = 0; ti < 2; ++ti) offA[ti] = swz(w * 32 + ti * 16 + cl, quad);
#pragma unroll
    for (int tj = 0; tj < 8; ++tj) offB[tj] = swz(tj * 16 + cl, quad);

    f32x4 acc[2][8];
#pragma unroll
    for (int i = 0; i < 2; ++i)
#pragma unroll
        for (int j = 0; j < 8; ++j) acc[i][j] = (f32x4){0.f, 0.f, 0.f, 0.f};

    // prologue: stage k=0 into buffer 0
    gl2lds16(gA, lds + tid * 16);
    gl2lds16(gA + (size_t)64 * GD, lds + 4096 + tid * 16);
    gl2lds16(gB, lds + 8192 + tid * 16);
    gl2lds16(gB + (size_t)64 * GD, lds + 12288 + tid * 16);

#pragma unroll 2
    for (int kk = 0; kk < KI; ++kk) {
        __syncthreads();  // buf[kk&1] staged; prior buf's ds_reads done

        // 1) read ALL fragments of this iter (10 x ds_read_b128)
        const char* Ab = lds + (kk & 1) * 16384;
        const char* Bb = Ab + 8192;
        l64x2 aF[2], bF[8];
#pragma unroll
        for (int ti = 0; ti < 2; ++ti) aF[ti] = *(const l64x2*)(Ab + offA[ti]);
#pragma unroll
        for (int tj = 0; tj < 8; ++tj) bF[tj] = *(const l64x2*)(Bb + offB[tj]);

        // 2) stage k+1 into the other buffer; drains at the next barrier
        if (kk + 1 < KI) {
            char* An = lds + ((kk + 1) & 1) * 16384;
            const int ko = (kk + 1) * 64;  // bytes along K
            gl2lds16(gA + ko, An + tid * 16);
            gl2lds16(gA + (size_t)64 * GD + ko, An + 4096 + tid * 16);
            gl2lds16(gB + ko, An + 8192 + tid * 16);
            gl2lds16(gB + (size_t)64 * GD + ko, An + 12288 + tid * 16);
        }

        // 3) 32 MFMAs: each b128 pair feeds two K=32 fp8 MFMAs
#pragma unroll
        for (int ti = 0; ti < 2; ++ti)
#pragma unroll
            for (int tj = 0; tj < 8; ++tj) {
                acc[ti][tj] = __builtin_amdgcn_mfma_f32_16x16x32_fp8_fp8(
                    aF[ti].x, bF[tj].x, acc[ti][tj], 0, 0, 0);
                acc[ti][tj] = __builtin_amdgcn_mfma_f32_16x16x32_fp8_fp8(
                    aF[ti].y, bF[tj].y, acc[ti][tj], 0, 0, 0);
            }
    }

    // ---------------- epilogue (base-2 state, base-cancelled deltas) ----------------
    const float t2 = 2.f * taub;
    const float pen = 100.f * taub;
    float ar[8];  // -taub * sq[row] for this lane's 8 rows
    int rowg[8];
#pragma unroll
    for (int ti = 0; ti < 2; ++ti)
#pragma unroll
        for (int rg = 0; rg < 4; ++rg) {
            int r = row_base + w * 32 + ti * 16 + quad * 4 + rg;
            rowg[ti * 4 + rg] = r;
            ar[ti * 4 + rg] = -taub * sq[r];
        }
    float ac[8];  // -taub * sq[col] for this lane's 8 cols
#pragma unroll
    for (int tj = 0; tj < 8; ++tj) ac[tj] = -taub * sq[col_base + tj * 16 + cl];

    float* pmJ = pm + (size_t)J * GN;
    float* psJ = ps + (size_t)J * GN;
    float* ptJ = pt + (size_t)J * GN;

    // ---- direct pass: reduce over cols; row term ar[idx] uniform across the
    // 16 reducing lanes AND the 8 values -> cancels in d; added once to m ----
#pragma unroll
    for (int ti = 0; ti < 2; ++ti)
#pragma unroll
        for (int rg = 0; rg < 4; ++rg) {
            const int idx = ti * 4 + rg;
            float uu[8];
            float mloc = -1e30f;
            if (I == J) {  // block-uniform: only diagonal tiles carry the penalty
#pragma unroll
                for (int tj = 0; tj < 8; ++tj) {
                    float u = fmaf(t2, acc[ti][tj][rg], ac[tj]);
                    if (rowg[idx] == col_base + tj * 16 + cl) u -= pen;
                    uu[tj] = u;
                    mloc = fmaxf(mloc, u);
                }
            } else {
#pragma unroll
                for (int tj = 0; tj < 8; ++tj) {
                    float u = fmaf(t2, acc[ti][tj][rg], ac[tj]);
                    uu[tj] = u;
                    mloc = fmaxf(mloc, u);
                }
            }
            mloc = qmax16(mloc);
            float s = 0.f, t = 0.f;
#pragma unroll
            for (int tj = 0; tj < 8; ++tj) {
                float d = uu[tj] - mloc;  // row term cancelled
                float e = hexp2(d);       // bare v_exp_f32
                s += e;
                t += e * d;
            }
            s = qsum16(s);
            t = qsum16(t);
            if (cl == 0) {
                int r = rowg[idx];
                pmJ[r] = mloc + ar[idx];  // base restored once
                psJ[r] = s;
                ptJ[r] = t;
            }
        }

    // ---- transposed pass: reduce over rows; col term ac[tj] uniform across
    // the reducing lanes/values -> cancels in d; added once to m ----
    if (I != J) {  // block-uniform branch
        __syncthreads();  // all K-loop LDS reads done before tmrg aliases the buffer
#pragma unroll
        for (int tj = 0; tj < 8; ++tj) {
            float uu[8];
            float mloc = -1e30f;
#pragma unroll
            for (int ti = 0; ti < 2; ++ti)
#pragma unroll
                for (int rg = 0; rg < 4; ++rg) {
                    float u = fmaf(t2, acc[ti][tj][rg], ar[ti * 4 + rg]);
                    uu[ti * 4 + rg] = u;
                    mloc = fmaxf(mloc, u);
                }
            mloc = fmaxf(mloc, __shfl_xor(mloc, 16));
            mloc = fmaxf(mloc, __shfl_xor(mloc, 32));
            float s = 0.f, t = 0.f;
#pragma unroll
            for (int k = 0; k < 8; ++k) {
                float d = uu[k] - mloc;
                float e = hexp2(d);
                s += e;
                t += e * d;
            }
            s += __shfl_xor(s, 16);
            t += __shfl_xor(t, 16);
            s += __shfl_xor(s, 32);
            t += __shfl_xor(t, 32);
            if (quad == 0) {
                int c = tj * 16 + cl;
                tmrg[c][w][0] = mloc + ac[tj];  // col term restored once
                tmrg[c][w][1] = s;
                tmrg[c][w][2] = t;
            }
        }
        __syncthreads();
        if (tid < 128) {
            float m = tmrg[tid][0][0], S = tmrg[tid][0][1], T = tmrg[tid][0][2];
#pragma unroll
            for (int ww = 1; ww < 4; ++ww) {
                float mc = tmrg[tid][ww][0], Sc = tmrg[tid][ww][1], Tc = tmrg[tid][ww][2];
                float mn = fmaxf(m, mc);
                float ea = hexp2(m - mn), eb = hexp2(mc - mn);
                T = (T + (m - mn) * S) * ea + (Tc + (mc - mn) * Sc) * eb;
                S = S * ea + Sc * eb;
                m = mn;
            }
            int c = col_base + tid;
            pm[(size_t)I * GN + c] = m;
            ps[(size_t)I * GN + c] = S;
            pt[(size_t)I * GN + c] = T;
        }
    }
}

// ------- Kernel 3: combine (base-2), coalesced + parallel -------
// entropy = ln2 * (log2(S) - T2/S); ln2 folded into the final atomic constant.
__global__ __launch_bounds__(256) void combine(const float* __restrict__ pm,
                                               const float* __restrict__ ps,
                                               const float* __restrict__ pt,
                                               const float* __restrict__ coefp,
                                               float* __restrict__ out) {
    const int t = threadIdx.x;
    const int r = t & 63;
    const int chunk = t >> 6;
    const int row = blockIdx.x * 64 + r;
    float m = -1e30f, S = 0.f, T = 0.f;
#pragma unroll
    for (int i = 0; i < 16; ++i) {
        const int c = chunk * 16 + i;
        float mc = pm[(size_t)c * GN + row];
        float Sc = ps[(size_t)c * GN + row];
        float Tc = pt[(size_t)c * GN + row];
        float mn = fmaxf(m, mc);
        float ea = __builtin_amdgcn_exp2f(m - mn), eb = __builtin_amdgcn_exp2f(mc - mn);
        T = (T + (m - mn) * S) * ea + (Tc + (mc - mn) * Sc) * eb;
        S = S * ea + Sc * eb;
        m = mn;
    }
    __shared__ float lm[4][64], lS[4][64], lT[4][64];
    lm[chunk][r] = m;
    lS[chunk][r] = S;
    lT[chunk][r] = T;
    __syncthreads();
    if (t < 64) {
        float M = lm[0][r], Sa = lS[0][r], Ta = lT[0][r];
#pragma unroll
        for (int cc = 1; cc < 4; ++cc) {
            float mc = lm[cc][r], Sc = lS[cc][r], Tc = lT[cc][r];
            float mn = fmaxf(M, mc);
            float ea = __builtin_amdgcn_exp2f(M - mn), eb = __builtin_amdgcn_exp2f(mc - mn);
            Ta = (Ta + (M - mn) * Sa) * ea + (Tc + (mc - mn) * Sc) * eb;
            Sa = Sa * ea + Sc * eb;
            M = mn;
        }
        float ent2 = __log2f(Sa) - Ta / Sa;  // base-2 row entropy (v_log_f32)
#pragma unroll
        for (int off = 1; off < 64; off <<= 1) ent2 += __shfl_xor(ent2, off);
        if (t == 0) atomicAdd(out, ent2 * coefp[0] * (LN2 / (float)GN));
    }
}

extern "C" void kernel_launch(void* const* d_in, const int* in_sizes, int n_in,
                              void* d_out, int out_size, void* d_ws, size_t ws_size,
                              hipStream_t stream) {
    const float* x = (const float*)d_in[0];      // 8192*768 fp32
    const float* coefp = (const float*)d_in[1];  // scalar
    const float* taup = (const float*)d_in[2];   // scalar
    float* out = (float*)d_out;

    char* ws = (char*)d_ws;
    unsigned char* xq = (unsigned char*)ws;              // 6,291,456 B (fp8)
    float* sq = (float*)(ws + 6291456);                  // 32,768 B
    float* pm = (float*)(ws + 6324224);                  // 2,097,152 B
    float* ps = (float*)(ws + 6324224 + 2097152);        // 2,097,152 B
    float* pt = (float*)(ws + 6324224 + 2 * 2097152);    // 2,097,152 B

    prep_kernel<<<GN / 4, 256, 0, stream>>>(x, xq, sq, out);
    sym_gemm_entropy<<<NTILE, 256, 0, stream>>>(xq, sq, taup, pm, ps, pt);
    combine<<<GN / 64, 256, 0, stream>>>(pm, ps, pt, coefp, out);
}